// Round 1
// baseline (1079.864 us; speedup 1.0000x reference)
//
#include <hip/hip_runtime.h>
#include <hip/hip_bf16.h>

typedef __bf16 bf16;
typedef __attribute__((ext_vector_type(8))) __bf16 bf16x8;
typedef __attribute__((ext_vector_type(4))) float f32x4;

constexpr int D_IN  = 512;
constexpr int D_HID = 256;
constexpr int D_OUT = 32;
constexpr int BM = 64;     // rows per block
constexpr int BK = 32;     // K chunk (one 16x16x32 MFMA deep)
constexpr int HPAD = 260;  // stride 260 bf16 = 130 dwords = 2 mod 32

// --- edge-pipeline bucketing ---
constexpr int RPB    = 128;   // rows per bucket (localrow fits in 7 bits)
constexpr int NB_MAX = 1024;  // max buckets supported by LDS histogram

#define GLOBAL_AS(p) ((const __attribute__((address_space(1))) void*)(p))
#define LDS_AS(p)    ((__attribute__((address_space(3))) void*)(p))

// ---------------- prep: W1 -> W1T (bf16, [n][k]), W2 -> W2T (bf16, [n][k]) --
__global__ __launch_bounds__(256) void prep_kernel(
    const float* __restrict__ W1, const float* __restrict__ W2,
    bf16* __restrict__ W1T, bf16* __restrict__ W2T)
{
    int idx = blockIdx.x * 256 + threadIdx.x;
    if (idx < D_IN * D_HID) {
        int k = idx / D_HID, n = idx % D_HID;
        W1T[n * D_IN + k] = (bf16)W1[idx];
    }
    int j = idx - D_IN * D_HID;
    if (j >= 0 && j < D_HID * D_OUT) {
        int k = j / D_OUT, n = j % D_OUT;
        W2T[n * D_HID + k] = (bf16)W2[j];
    }
}

// ---------------- fused MLP: X = relu(feat@W1 + b1) @ W2 + b2 ---------------
__global__ __launch_bounds__(256) void fused_mlp_kernel(
    const float* __restrict__ feat,
    const bf16* __restrict__ W1T, const bf16* __restrict__ W2T,
    const float* __restrict__ b1, const float* __restrict__ b2,
    float* __restrict__ X, int N)
{
    // Hsm aliases (Asm | Bsm): staging is dead once the K-loop finishes.
    __shared__ __align__(16) char smem[(BM + D_OUT) * HPAD * sizeof(bf16)];
    bf16* Asm  = (bf16*)smem;                         // [BM][BK]
    bf16* Bsm  = (bf16*)(smem + BM * BK * 2);         // [D_HID][BK]
    bf16* Hsm  = (bf16*)smem;                         // [BM][HPAD]
    bf16* B2sm = (bf16*)(smem + BM * HPAD * 2);       // [D_OUT][HPAD]

    const int tid  = threadIdx.x;
    const int wave = tid >> 6;
    const int lane = tid & 63;
    const int ln   = lane & 15;   // MFMA row/col index
    const int q    = lane >> 4;   // quad 0..3
    const int mw   = wave * 16;   // wave's row block within tile
    const int r0   = blockIdx.x * BM;

    // Stage W2T -> B2sm once
    #pragma unroll
    for (int i = 0; i < 4; ++i) {
        int c  = tid + i * 256;        // chunk id 0..1023
        int n  = c >> 5;               // 32 chunks per n-row -> n 0..31
        int kc = (c & 31) * 8;
        *(bf16x8*)&B2sm[n * HPAD + kc] = *(const bf16x8*)&W2T[n * D_HID + kc];
    }

    f32x4 acc[16] = {};  // 16 n-tiles of 16x16 per wave (full D_HID)

    const int am   = tid >> 2;           // 0..63
    const int asub = (tid & 3) * 8;      // 0,8,16,24
    const long arow = (long)min(r0 + am, N - 1);
    const float* asrc = feat + arow * D_IN + asub;

    for (int k0 = 0; k0 < D_IN; k0 += BK) {
        #pragma unroll
        for (int i = 0; i < 4; ++i) {
            int c = i * 256 + wave * 64 + lane;
            const bf16* gsrc = W1T + ((c >> 2) * D_IN + k0 + (c & 3) * 8);
            bf16* lbase = Bsm + (i * 256 + wave * 64) * 8;  // wave-uniform
            __builtin_amdgcn_global_load_lds(GLOBAL_AS(gsrc), LDS_AS(lbase), 16, 0, 0);
        }

        float4 f0 = *(const float4*)(asrc + k0);
        float4 f1 = *(const float4*)(asrc + k0 + 4);
        bf16x8 av;
        av[0] = (bf16)f0.x; av[1] = (bf16)f0.y; av[2] = (bf16)f0.z; av[3] = (bf16)f0.w;
        av[4] = (bf16)f1.x; av[5] = (bf16)f1.y; av[6] = (bf16)f1.z; av[7] = (bf16)f1.w;
        *(bf16x8*)&Asm[am * BK + asub] = av;

        __syncthreads();

        bf16x8 af = *(const bf16x8*)&Asm[(mw + ln) * BK + q * 8];
        #pragma unroll
        for (int t = 0; t < 16; ++t) {
            bf16x8 bfv = *(const bf16x8*)&Bsm[(t * 16 + ln) * BK + q * 8];
            acc[t] = __builtin_amdgcn_mfma_f32_16x16x32_bf16(af, bfv, acc[t], 0, 0, 0);
        }
        __syncthreads();
    }

    // Epilogue 1: h = relu(acc + b1) -> Hsm
    #pragma unroll
    for (int t = 0; t < 16; ++t) {
        int colh = t * 16 + ln;
        float bb = b1[colh];
        #pragma unroll
        for (int i = 0; i < 4; ++i) {
            int row = mw + q * 4 + i;
            float v = acc[t][i] + bb;
            Hsm[row * HPAD + colh] = (bf16)fmaxf(v, 0.0f);
        }
    }
    __syncthreads();

    // GEMM2: X_tile = Hsm @ W2 (K=256, N=32)
    f32x4 acc2[2] = {};
    #pragma unroll
    for (int k0 = 0; k0 < D_HID; k0 += BK) {
        bf16x8 af = *(const bf16x8*)&Hsm[(mw + ln) * HPAD + k0 + q * 8];
        #pragma unroll
        for (int t = 0; t < 2; ++t) {
            bf16x8 bfv = *(const bf16x8*)&B2sm[(t * 16 + ln) * HPAD + k0 + q * 8];
            acc2[t] = __builtin_amdgcn_mfma_f32_16x16x32_bf16(af, bfv, acc2[t], 0, 0, 0);
        }
    }

    // Epilogue 2: X = acc2 + b2 (fp32)
    #pragma unroll
    for (int t = 0; t < 2; ++t) {
        int c = t * 16 + ln;
        float bb = b2[c];
        #pragma unroll
        for (int i = 0; i < 4; ++i) {
            int row = r0 + mw + q * 4 + i;
            if (row < N) X[row * D_OUT + c] = acc2[t][i] + bb;
        }
    }
}

// ---------------- bucket histogram: 2048 edges/block, LDS-local -------------
__global__ __launch_bounds__(256) void bhist_kernel(
    const int* __restrict__ Arow, int* __restrict__ bcnt, int E, int NB)
{
    __shared__ int h[NB_MAX];
    for (int i = threadIdx.x; i < NB; i += 256) h[i] = 0;
    __syncthreads();
    int base = blockIdx.x * 2048 + threadIdx.x;
    #pragma unroll
    for (int j = 0; j < 8; ++j) {
        int e = base + j * 256;
        if (e < E) atomicAdd(&h[Arow[e] >> 7], 1);
    }
    __syncthreads();
    for (int i = threadIdx.x; i < NB; i += 256) {
        int c = h[i];
        if (c) atomicAdd(&bcnt[i], c);
    }
}

// ---------------- bucket scan: single block, NB <= 1024 ---------------------
__global__ __launch_bounds__(256) void bscan_kernel(
    const int* __restrict__ bcnt, int* __restrict__ boffs,
    int* __restrict__ bcur, int NB)
{
    __shared__ int lds[256];
    int t = threadIdx.x;
    int v[4];
    int s = 0;
    #pragma unroll
    for (int j = 0; j < 4; ++j) {
        int i = t * 4 + j;
        v[j] = (i < NB) ? bcnt[i] : 0;
        s += v[j];
    }
    lds[t] = s;
    __syncthreads();
    for (int d = 1; d < 256; d <<= 1) {
        int x = (t >= d) ? lds[t - d] : 0;
        __syncthreads();
        lds[t] += x;
        __syncthreads();
    }
    int run = lds[t] - s;
    #pragma unroll
    for (int j = 0; j < 4; ++j) {
        int i = t * 4 + j;
        if (i < NB) { boffs[i] = run; bcur[i] = run; }
        run += v[j];
    }
    if (t == 255) boffs[NB] = lds[255];
}

// ---------------- bucket fill: append packed (localrow|col, data) records ---
// Frontier = NB (~782) cache lines -> stays L2-resident -> writes combine.
__global__ __launch_bounds__(256) void bfill_kernel(
    const int* __restrict__ Arow, const int* __restrict__ Acol,
    const float* __restrict__ Adata, int* __restrict__ bcur,
    int2* __restrict__ recs, int E)
{
    int e = blockIdx.x * 256 + threadIdx.x;
    if (e >= E) return;
    int r = Arow[e];
    int p = atomicAdd(&bcur[r >> 7], 1);
    int2 pk;
    pk.x = ((r & (RPB - 1)) << 25) | Acol[e];   // 7b localrow | 25b col
    pk.y = __float_as_int(Adata[e]);
    recs[p] = pk;
}

// ---------------- bucket reduce: LDS fp32 accumulate, one block/bucket ------
__global__ __launch_bounds__(256) void breduce_kernel(
    const int* __restrict__ boffs, const int2* __restrict__ recs,
    const float* __restrict__ X, float* __restrict__ out, int N)
{
    // pad stride 33 dwords: bank = (lr*33 + d) % 32 = (lr + d) % 32 -> spread
    __shared__ float acc[RPB * 33];
    int t = threadIdx.x;
    for (int i = t; i < RPB * 33; i += 256) acc[i] = 0.0f;
    __syncthreads();

    int b     = blockIdx.x;
    int start = boffs[b];
    int end   = boffs[b + 1];
    int slot  = t >> 3;   // record slot 0..31
    int dg    = t & 7;    // dim group: dims 4*dg..4*dg+3

    for (int i = start + slot; i < end; i += 32) {
        int2  pk  = recs[i];                 // broadcast across 8 dg lanes
        int   lr  = ((unsigned)pk.x) >> 25;
        int   col = pk.x & ((1 << 25) - 1);
        float a   = __int_as_float(pk.y);
        f32x4 x   = *(const f32x4*)(X + (long)col * D_OUT + dg * 4);
        float* ap = &acc[lr * 33 + dg * 4];
        atomicAdd(ap + 0, a * x[0]);
        atomicAdd(ap + 1, a * x[1]);
        atomicAdd(ap + 2, a * x[2]);
        atomicAdd(ap + 3, a * x[3]);
    }
    __syncthreads();

    long r0 = (long)b * RPB;
    for (int c = t; c < RPB * 8; c += 256) {
        int row = c >> 3, g = c & 7;
        long gr = r0 + row;
        if (gr < N) {
            f32x4 v = { acc[row * 33 + g * 4 + 0], acc[row * 33 + g * 4 + 1],
                        acc[row * 33 + g * 4 + 2], acc[row * 33 + g * 4 + 3] };
            *(f32x4*)(out + gr * D_OUT + g * 4) = v;
        }
    }
}

// ---------------- fallback scatter (if ws too small / N too big) ------------
__global__ __launch_bounds__(256) void scatter_kernel(
    const float* __restrict__ Adata, const int* __restrict__ Arow,
    const int* __restrict__ Acol, const float* __restrict__ X,
    float* __restrict__ out, int E)
{
    int idx = blockIdx.x * 256 + threadIdx.x;
    int e = idx >> 3;
    int g = idx & 7;
    if (e >= E) return;
    int   col = Acol[e];
    int   row = Arow[e];
    float a   = Adata[e];
    float4 x = *(const float4*)(X + (long)col * D_OUT + g * 4);
    float* o = out + (long)row * D_OUT + g * 4;
    unsafeAtomicAdd(o + 0, a * x.x);
    unsafeAtomicAdd(o + 1, a * x.y);
    unsafeAtomicAdd(o + 2, a * x.z);
    unsafeAtomicAdd(o + 3, a * x.w);
}

// ---------------- launch ----------------------------------------------------
extern "C" void kernel_launch(void* const* d_in, const int* in_sizes, int n_in,
                              void* d_out, int out_size, void* d_ws, size_t ws_size,
                              hipStream_t stream)
{
    const float* feat  = (const float*)d_in[0];
    const float* Adata = (const float*)d_in[1];
    const float* W1    = (const float*)d_in[2];
    const float* b1    = (const float*)d_in[3];
    const float* W2    = (const float*)d_in[4];
    const float* b2    = (const float*)d_in[5];
    const int*   Arow  = (const int*)d_in[6];
    const int*   Acol  = (const int*)d_in[7];

    const int N = in_sizes[0] / D_IN;
    const int E = in_sizes[1];
    const int NB = (N + RPB - 1) / RPB;

    // --- workspace carve-out (256B aligned segments) ---
    char* p = (char*)d_ws;
    auto alloc = [&](size_t bytes) {
        char* q = p;
        p += (bytes + 255) & ~(size_t)255;
        return q;
    };
    float* X     = (float*)alloc((size_t)N * D_OUT * sizeof(float));
    bf16*  W1T   = (bf16*) alloc((size_t)D_IN * D_HID * sizeof(bf16));
    bf16*  W2T   = (bf16*) alloc((size_t)D_HID * D_OUT * sizeof(bf16));
    int*   bcnt  = (int*)  alloc((size_t)NB * sizeof(int));
    int*   boffs = (int*)  alloc((size_t)(NB + 1) * sizeof(int));
    int*   bcur  = (int*)  alloc((size_t)NB * sizeof(int));
    int2*  recs  = (int2*) alloc((size_t)E * sizeof(int2));
    size_t need = (size_t)(p - (char*)d_ws);
    const bool use_bucket = (need <= ws_size) && (NB <= NB_MAX) && (N <= (1 << 25));

    float* out = (float*)d_out;

    int prep_elems = D_IN * D_HID + D_HID * D_OUT;
    prep_kernel<<<(prep_elems + 255) / 256, 256, 0, stream>>>(W1, W2, W1T, W2T);

    fused_mlp_kernel<<<(N + BM - 1) / BM, 256, 0, stream>>>(
        feat, W1T, W2T, b1, b2, X, N);

    if (use_bucket) {
        hipMemsetAsync(bcnt, 0, (size_t)NB * sizeof(int), stream);
        bhist_kernel<<<(E + 2047) / 2048, 256, 0, stream>>>(Arow, bcnt, E, NB);
        bscan_kernel<<<1, 256, 0, stream>>>(bcnt, boffs, bcur, NB);
        bfill_kernel<<<(E + 255) / 256, 256, 0, stream>>>(
            Arow, Acol, Adata, bcur, recs, E);
        breduce_kernel<<<NB, 256, 0, stream>>>(boffs, recs, X, out, N);
    } else {
        hipMemsetAsync(out, 0, (size_t)out_size * sizeof(float), stream);
        long scatter_threads = (long)E * 8;
        scatter_kernel<<<(scatter_threads + 255) / 256, 256, 0, stream>>>(
            Adata, Arow, Acol, X, out, E);
    }
}

// Round 3
// 544.678 us; speedup vs baseline: 1.9826x; 1.9826x over previous
//
#include <hip/hip_runtime.h>
#include <hip/hip_bf16.h>

typedef __bf16 bf16;
typedef __attribute__((ext_vector_type(8))) __bf16 bf16x8;
typedef __attribute__((ext_vector_type(4))) float f32x4;

constexpr int D_IN  = 512;
constexpr int D_HID = 256;
constexpr int D_OUT = 32;
constexpr int BM = 64;     // rows per block
constexpr int BK = 32;     // K chunk (one 16x16x32 MFMA deep)
constexpr int HPAD = 260;  // stride 260 bf16 = 130 dwords = 2 mod 32
constexpr int SCAN_VPT  = 8;
constexpr int SCAN_SPAN = 2048;  // 256 threads * 8
constexpr int NSLICE = 8;        // XCD count: reorder writer partitioning

#define GLOBAL_AS(p) ((const __attribute__((address_space(1))) void*)(p))
#define LDS_AS(p)    ((__attribute__((address_space(3))) void*)(p))

// ---------------- prep: W1 -> W1T (bf16, [n][k]), W2 -> W2T (bf16, [n][k]) --
__global__ __launch_bounds__(256) void prep_kernel(
    const float* __restrict__ W1, const float* __restrict__ W2,
    bf16* __restrict__ W1T, bf16* __restrict__ W2T)
{
    int idx = blockIdx.x * 256 + threadIdx.x;
    if (idx < D_IN * D_HID) {
        int k = idx / D_HID, n = idx % D_HID;
        W1T[n * D_IN + k] = (bf16)W1[idx];
    }
    int j = idx - D_IN * D_HID;
    if (j >= 0 && j < D_HID * D_OUT) {
        int k = j / D_OUT, n = j % D_OUT;
        W2T[n * D_HID + k] = (bf16)W2[j];
    }
}

// ---------------- fused MLP: X = relu(feat@W1 + b1) @ W2 + b2 ---------------
// Round-0 verified sync structure (stage -> sync -> read -> sync, single Bsm).
// Only change: A fragment loaded global->reg directly (dataflow-identical to
// the old Asm round-trip: lane (q,ln) gets feat[r0+mw+ln][k0+q*8 .. +7]).
__global__ __launch_bounds__(256) void fused_mlp_kernel(
    const float* __restrict__ feat,
    const bf16* __restrict__ W1T, const bf16* __restrict__ W2T,
    const float* __restrict__ b1, const float* __restrict__ b2,
    float* __restrict__ X, int N)
{
    // layout: [0,16384) Bsm (staging, dead after K-loop)
    //         [0,33280) Hsm (aliases Bsm)   [33280,49920) B2sm
    __shared__ __align__(16) char smem[(BM + D_OUT) * HPAD * sizeof(bf16)];
    bf16* Bsm  = (bf16*)smem;                         // [D_HID][BK]
    bf16* Hsm  = (bf16*)smem;                         // [BM][HPAD]
    bf16* B2sm = (bf16*)(smem + BM * HPAD * 2);       // [D_OUT][HPAD]

    const int tid  = threadIdx.x;
    const int wave = tid >> 6;
    const int lane = tid & 63;
    const int ln   = lane & 15;   // MFMA row/col index
    const int q    = lane >> 4;   // quad 0..3
    const int mw   = wave * 16;   // wave's row block within tile
    const int r0   = blockIdx.x * BM;

    // Stage W2T -> B2sm once: 32 rows x 256 bf16 = 1024 x 16B chunks
    #pragma unroll
    for (int i = 0; i < 4; ++i) {
        int c  = tid + i * 256;        // chunk id 0..1023
        int n  = c >> 5;               // 32 chunks per n-row -> n 0..31
        int kc = (c & 31) * 8;
        *(bf16x8*)&B2sm[n * HPAD + kc] = *(const bf16x8*)&W2T[n * D_HID + kc];
    }

    f32x4 acc[16] = {};  // 16 n-tiles of 16x16 per wave (full D_HID)

    // A source: lane (q,ln) owns row mw+ln, k-slice q*8..q*8+7 (fragment layout)
    const long arow = (long)min(r0 + mw + ln, N - 1);
    const float* asrc = feat + arow * D_IN + q * 8;

    for (int k0 = 0; k0 < D_IN; k0 += BK) {
        // async stage B chunk from W1T (identical to round-0 passing version)
        #pragma unroll
        for (int i = 0; i < 4; ++i) {
            int c = i * 256 + wave * 64 + lane;
            const bf16* gsrc = W1T + ((c >> 2) * D_IN + k0 + (c & 3) * 8);
            bf16* lbase = Bsm + (i * 256 + wave * 64) * 8;  // wave-uniform
            __builtin_amdgcn_global_load_lds(GLOBAL_AS(gsrc), LDS_AS(lbase), 16, 0, 0);
        }

        // A fragment: direct global -> registers
        float4 f0 = *(const float4*)(asrc + k0);
        float4 f1 = *(const float4*)(asrc + k0 + 4);
        bf16x8 af;
        af[0] = (bf16)f0.x; af[1] = (bf16)f0.y; af[2] = (bf16)f0.z; af[3] = (bf16)f0.w;
        af[4] = (bf16)f1.x; af[5] = (bf16)f1.y; af[6] = (bf16)f1.z; af[7] = (bf16)f1.w;

        __syncthreads();   // drains global_load_lds (compiler vmcnt(0) pre-barrier)

        #pragma unroll
        for (int t = 0; t < 16; ++t) {
            bf16x8 bfv = *(const bf16x8*)&Bsm[(t * 16 + ln) * BK + q * 8];
            acc[t] = __builtin_amdgcn_mfma_f32_16x16x32_bf16(af, bfv, acc[t], 0, 0, 0);
        }
        __syncthreads();   // protect Bsm for next iteration's staging
    }

    // Epilogue 1: h = relu(acc + b1) -> Hsm (bf16, A-operand layout for GEMM2)
    // (Hsm aliases the staging buffer; the trailing K-loop barrier guards it.)
    #pragma unroll
    for (int t = 0; t < 16; ++t) {
        int colh = t * 16 + ln;
        float bb = b1[colh];
        #pragma unroll
        for (int i = 0; i < 4; ++i) {
            int row = mw + q * 4 + i;
            float v = acc[t][i] + bb;
            Hsm[row * HPAD + colh] = (bf16)fmaxf(v, 0.0f);
        }
    }
    __syncthreads();

    // GEMM2: X_tile = Hsm @ W2 (K=256, N=32) — 2 n-tiles per wave
    f32x4 acc2[2] = {};
    #pragma unroll
    for (int k0 = 0; k0 < D_HID; k0 += BK) {
        bf16x8 af2 = *(const bf16x8*)&Hsm[(mw + ln) * HPAD + k0 + q * 8];
        #pragma unroll
        for (int t = 0; t < 2; ++t) {
            bf16x8 bfv = *(const bf16x8*)&B2sm[(t * 16 + ln) * HPAD + k0 + q * 8];
            acc2[t] = __builtin_amdgcn_mfma_f32_16x16x32_bf16(af2, bfv, acc2[t], 0, 0, 0);
        }
    }

    // Epilogue 2: X = acc2 + b2 (fp32)
    #pragma unroll
    for (int t = 0; t < 2; ++t) {
        int c = t * 16 + ln;
        float bb = b2[c];
        #pragma unroll
        for (int i = 0; i < 4; ++i) {
            int row = r0 + mw + q * 4 + i;
            if (row < N) X[row * D_OUT + c] = acc2[t][i] + bb;
        }
    }
}

// ---------------- CSR build: histogram -> scan -> reorder -------------------
__global__ __launch_bounds__(256) void hist_kernel(
    const int* __restrict__ Arow, int* __restrict__ counts, int E)
{
    int e = blockIdx.x * 256 + threadIdx.x;
    if (e < E) atomicAdd(&counts[Arow[e]], 1);
}

__global__ __launch_bounds__(256) void scanA_kernel(
    const int* __restrict__ counts, int* __restrict__ offs,
    int* __restrict__ partials, int N)
{
    __shared__ int lds[256];
    int t = threadIdx.x;
    int base = blockIdx.x * SCAN_SPAN + t * SCAN_VPT;
    int v[SCAN_VPT];
    int tsum = 0;
    #pragma unroll
    for (int j = 0; j < SCAN_VPT; ++j) {
        v[j] = (base + j < N) ? counts[base + j] : 0;
        tsum += v[j];
    }
    lds[t] = tsum;
    __syncthreads();
    for (int d = 1; d < 256; d <<= 1) {
        int x = (t >= d) ? lds[t - d] : 0;
        __syncthreads();
        lds[t] += x;
        __syncthreads();
    }
    int run = lds[t] - tsum;
    #pragma unroll
    for (int j = 0; j < SCAN_VPT; ++j) {
        if (base + j < N) offs[base + j] = run;
        run += v[j];
    }
    if (t == 255) partials[blockIdx.x] = lds[255];
}

__global__ __launch_bounds__(256) void scanB_kernel(int* __restrict__ partials, int nb)
{
    __shared__ int lds[256];
    int t = threadIdx.x;
    int v = (t < nb) ? partials[t] : 0;
    lds[t] = v;
    __syncthreads();
    for (int d = 1; d < 256; d <<= 1) {
        int x = (t >= d) ? lds[t - d] : 0;
        __syncthreads();
        lds[t] += x;
        __syncthreads();
    }
    if (t < nb) partials[t] = lds[t] - v;
}

__global__ __launch_bounds__(256) void scanC_kernel(
    int* __restrict__ offs, const int* __restrict__ partials,
    int* __restrict__ cursor, int N)
{
    int i = blockIdx.x * 256 + threadIdx.x;
    if (i < N) {
        int o = offs[i] + partials[i / SCAN_SPAN];
        offs[i] = o;
        cursor[i] = o;
    }
}

// ---------------- reorder, XCD-writer-partitioned ---------------------------
// Grid = NSLICE * ceil(E/256). Block b: edge chunk b>>3, row slice b&7.
// Each edge is seen by 8 blocks (one per slice) and appended by exactly the
// one whose slice contains its row -> correctness independent of dispatch.
// With round-robin block->XCD mapping, each CSR row region has ONE writing
// XCD -> exclusive L2 ownership of frontier lines -> full-line evictions
// (kills cross-XCD partial-line write amp) + no cross-XCD cursor bouncing.
__global__ __launch_bounds__(256) void reorder_kernel(
    const int* __restrict__ Arow, const int* __restrict__ Acol,
    const float* __restrict__ Adata, int* __restrict__ cursor,
    int2* __restrict__ pairs, int E, int rps)
{
    int b = blockIdx.x;
    int slice = b & (NSLICE - 1);
    int e = (b >> 3) * 256 + threadIdx.x;
    if (e >= E) return;
    int r = Arow[e];
    if ((unsigned)(r - slice * rps) >= (unsigned)rps) return;
    int p = atomicAdd(&cursor[r], 1);
    int2 pk;
    pk.x = Acol[e];
    pk.y = __float_as_int(Adata[e]);
    pairs[p] = pk;  // single 8B store; frontier lines owned by one XCD
}

// ---------------- reduce: one wave per row, 8 edges in flight ---------------
__global__ __launch_bounds__(256) void reduce_kernel(
    const int* __restrict__ offs, const int* __restrict__ counts,
    const int2* __restrict__ pairs, const float* __restrict__ X,
    float* __restrict__ out, int N)
{
    int w    = threadIdx.x >> 6;
    int lane = threadIdx.x & 63;
    int r    = blockIdx.x * 4 + w;
    if (r >= N) return;
    int slot = lane >> 3;    // edge slot 0..7
    int dg   = lane & 7;     // dim group: dims 4*dg..4*dg+3
    int off  = offs[r];
    int deg  = counts[r];
    f32x4 acc = {0.0f, 0.0f, 0.0f, 0.0f};
    for (int i = slot; i < deg; i += 8) {
        int2  pk = pairs[off + i];       // broadcast across the 8 dg lanes
        float a  = __int_as_float(pk.y);
        f32x4 x  = *(const f32x4*)(X + (long)pk.x * D_OUT + dg * 4);
        acc += a * x;
    }
    // butterfly over slots (strides 8,16,32)
    #pragma unroll
    for (int d = 8; d < 64; d <<= 1) {
        acc[0] += __shfl_xor(acc[0], d, 64);
        acc[1] += __shfl_xor(acc[1], d, 64);
        acc[2] += __shfl_xor(acc[2], d, 64);
        acc[3] += __shfl_xor(acc[3], d, 64);
    }
    if (slot == 0) *(f32x4*)(out + (long)r * D_OUT + dg * 4) = acc;
}

// ---------------- fallback scatter (if ws too small) ------------------------
__global__ __launch_bounds__(256) void scatter_kernel(
    const float* __restrict__ Adata, const int* __restrict__ Arow,
    const int* __restrict__ Acol, const float* __restrict__ X,
    float* __restrict__ out, int E)
{
    int idx = blockIdx.x * 256 + threadIdx.x;
    int e = idx >> 3;
    int g = idx & 7;
    if (e >= E) return;
    int   col = Acol[e];
    int   row = Arow[e];
    float a   = Adata[e];
    float4 x = *(const float4*)(X + (long)col * D_OUT + g * 4);
    float* o = out + (long)row * D_OUT + g * 4;
    unsafeAtomicAdd(o + 0, a * x.x);
    unsafeAtomicAdd(o + 1, a * x.y);
    unsafeAtomicAdd(o + 2, a * x.z);
    unsafeAtomicAdd(o + 3, a * x.w);
}

// ---------------- launch ----------------------------------------------------
extern "C" void kernel_launch(void* const* d_in, const int* in_sizes, int n_in,
                              void* d_out, int out_size, void* d_ws, size_t ws_size,
                              hipStream_t stream)
{
    const float* feat  = (const float*)d_in[0];
    const float* Adata = (const float*)d_in[1];
    const float* W1    = (const float*)d_in[2];
    const float* b1    = (const float*)d_in[3];
    const float* W2    = (const float*)d_in[4];
    const float* b2    = (const float*)d_in[5];
    const int*   Arow  = (const int*)d_in[6];
    const int*   Acol  = (const int*)d_in[7];

    const int N = in_sizes[0] / D_IN;
    const int E = in_sizes[1];

    // --- workspace carve-out (256B aligned segments) ---
    char* p = (char*)d_ws;
    auto alloc = [&](size_t bytes) {
        char* q = p;
        p += (bytes + 255) & ~(size_t)255;
        return q;
    };
    float* X       = (float*)alloc((size_t)N * D_OUT * sizeof(float));
    bf16*  W1T     = (bf16*) alloc((size_t)D_IN * D_HID * sizeof(bf16));
    bf16*  W2T     = (bf16*) alloc((size_t)D_HID * D_OUT * sizeof(bf16));
    int*   counts  = (int*)  alloc((size_t)N * sizeof(int));
    int*   offs    = (int*)  alloc((size_t)N * sizeof(int));
    int*   cursor  = (int*)  alloc((size_t)N * sizeof(int));
    int*   partials= (int*)  alloc(256 * sizeof(int));
    int2*  pairs   = (int2*) alloc((size_t)E * sizeof(int2));
    size_t need = (size_t)(p - (char*)d_ws);
    const bool use_csr = (need <= ws_size);

    float* out = (float*)d_out;

    int prep_elems = D_IN * D_HID + D_HID * D_OUT;
    prep_kernel<<<(prep_elems + 255) / 256, 256, 0, stream>>>(W1, W2, W1T, W2T);

    fused_mlp_kernel<<<(N + BM - 1) / BM, 256, 0, stream>>>(
        feat, W1T, W2T, b1, b2, X, N);

    if (use_csr) {
        hipMemsetAsync(counts, 0, (size_t)N * sizeof(int), stream);
        hist_kernel<<<(E + 255) / 256, 256, 0, stream>>>(Arow, counts, E);
        int nb = (N + SCAN_SPAN - 1) / SCAN_SPAN;   // 49 for N=100000 (<=256)
        scanA_kernel<<<nb, 256, 0, stream>>>(counts, offs, partials, N);
        scanB_kernel<<<1, 256, 0, stream>>>(partials, nb);
        scanC_kernel<<<(N + 255) / 256, 256, 0, stream>>>(offs, partials, cursor, N);
        int rps = (N + NSLICE - 1) / NSLICE;
        reorder_kernel<<<NSLICE * ((E + 255) / 256), 256, 0, stream>>>(
            Arow, Acol, Adata, cursor, pairs, E, rps);
        reduce_kernel<<<(N + 3) / 4, 256, 0, stream>>>(
            offs, counts, pairs, X, out, N);
    } else {
        hipMemsetAsync(out, 0, (size_t)out_size * sizeof(float), stream);
        long scatter_threads = (long)E * 8;
        scatter_kernel<<<(scatter_threads + 255) / 256, 256, 0, stream>>>(
            Adata, Arow, Acol, X, out, E);
    }
}

// Round 4
// 535.457 us; speedup vs baseline: 2.0167x; 1.0172x over previous
//
#include <hip/hip_runtime.h>
#include <hip/hip_bf16.h>

typedef __bf16 bf16;
typedef __attribute__((ext_vector_type(8))) __bf16 bf16x8;
typedef __attribute__((ext_vector_type(4))) float f32x4;

constexpr int D_IN  = 512;
constexpr int D_HID = 256;
constexpr int D_OUT = 32;
constexpr int BM = 64;     // rows per block
constexpr int BK = 32;     // K chunk (one 16x16x32 MFMA deep)
constexpr int HPAD = 260;  // stride 260 bf16 = 130 dwords = 2 mod 32
constexpr int SCAN_VPT  = 8;
constexpr int SCAN_SPAN = 2048;  // 256 threads * 8
constexpr int NSLICE = 8;        // XCD count: reorder writer partitioning

#define GLOBAL_AS(p) ((const __attribute__((address_space(1))) void*)(p))
#define LDS_AS(p)    ((__attribute__((address_space(3))) void*)(p))

// ---------------- prep: W1 -> W1T (bf16, [n][k]), W2 -> W2T (bf16, [n][k]) --
__global__ __launch_bounds__(256) void prep_kernel(
    const float* __restrict__ W1, const float* __restrict__ W2,
    bf16* __restrict__ W1T, bf16* __restrict__ W2T)
{
    int idx = blockIdx.x * 256 + threadIdx.x;
    if (idx < D_IN * D_HID) {
        int k = idx / D_HID, n = idx % D_HID;
        W1T[n * D_IN + k] = (bf16)W1[idx];
    }
    int j = idx - D_IN * D_HID;
    if (j >= 0 && j < D_HID * D_OUT) {
        int k = j / D_OUT, n = j % D_OUT;
        W2T[n * D_HID + k] = (bf16)W2[j];
    }
}

// ---------------- fused MLP: X = relu(feat@W1 + b1) @ W2 + b2 ---------------
// Round-3 verified sync structure (stage -> sync -> MFMA -> sync, single Bsm).
// Round-4 deltas (both sync-free):
//  * Bsm XOR-swizzle via SOURCE permutation: global_load_lds dest stays
//    linear (rule: gload_lds can't scatter); the global slot index is
//    XOR-permuted at stage time, ds_read applies the same involution.
//    Kills the 8-way bank conflict on the B-fragment reads (2 lanes/bank).
//  * B2sm removed: GEMM2 B-fragments load straight from W2T (16 KB, L2-hot).
//    LDS 50.2 KB -> 33.3 KB => 4 blocks/CU instead of 2.
__global__ __launch_bounds__(256) void fused_mlp_kernel(
    const float* __restrict__ feat,
    const bf16* __restrict__ W1T, const bf16* __restrict__ W2T,
    const float* __restrict__ b1, const float* __restrict__ b2,
    float* __restrict__ X, int N)
{
    // layout: [0,16384) Bsm (staging, dead after K-loop)
    //         [0,33280) Hsm (aliases Bsm)
    __shared__ __align__(16) char smem[BM * HPAD * sizeof(bf16)];
    bf16* Bsm  = (bf16*)smem;                         // [D_HID][BK], swizzled
    bf16* Hsm  = (bf16*)smem;                         // [BM][HPAD]

    const int tid  = threadIdx.x;
    const int wave = tid >> 6;
    const int lane = tid & 63;
    const int ln   = lane & 15;   // MFMA row/col index
    const int q    = lane >> 4;   // quad 0..3
    const int mw   = wave * 16;   // wave's row block within tile
    const int r0   = blockIdx.x * BM;

    f32x4 acc[16] = {};  // 16 n-tiles of 16x16 per wave (full D_HID)

    // A source: lane (q,ln) owns row mw+ln, k-slice q*8..q*8+7 (fragment layout)
    const long arow = (long)min(r0 + mw + ln, N - 1);
    const float* asrc = feat + arow * D_IN + q * 8;

    // physical slot this lane reads from the swizzled Bsm (involution of the
    // staging-side slot permutation; constant across t and k0)
    const int psl = q ^ ((ln >> 1) & 3);

    for (int k0 = 0; k0 < D_IN; k0 += BK) {
        // async stage B chunk from W1T. LDS dest byte = 16*c (linear, as
        // gload_lds requires); the GLOBAL slot is permuted so that phys slot
        // s of row r holds logical slot s ^ ((r>>1)&3). r = c>>2.
        #pragma unroll
        for (int i = 0; i < 4; ++i) {
            int c  = i * 256 + wave * 64 + lane;
            int sl = (c & 3) ^ ((c >> 3) & 3);
            const bf16* gsrc = W1T + ((c >> 2) * D_IN + k0 + sl * 8);
            bf16* lbase = Bsm + (i * 256 + wave * 64) * 8;  // wave-uniform
            __builtin_amdgcn_global_load_lds(GLOBAL_AS(gsrc), LDS_AS(lbase), 16, 0, 0);
        }

        // A fragment: direct global -> registers
        float4 f0 = *(const float4*)(asrc + k0);
        float4 f1 = *(const float4*)(asrc + k0 + 4);
        bf16x8 af;
        af[0] = (bf16)f0.x; af[1] = (bf16)f0.y; af[2] = (bf16)f0.z; af[3] = (bf16)f0.w;
        af[4] = (bf16)f1.x; af[5] = (bf16)f1.y; af[6] = (bf16)f1.z; af[7] = (bf16)f1.w;

        __syncthreads();   // drains global_load_lds (compiler vmcnt(0) pre-barrier)

        #pragma unroll
        for (int t = 0; t < 16; ++t) {
            // logical (row t*16+ln, slot q) lives at phys slot psl
            bf16x8 bfv = *(const bf16x8*)&Bsm[(t * 16 + ln) * BK + psl * 8];
            acc[t] = __builtin_amdgcn_mfma_f32_16x16x32_bf16(af, bfv, acc[t], 0, 0, 0);
        }
        __syncthreads();   // protect Bsm for next iteration's staging
    }

    // Epilogue 1: h = relu(acc + b1) -> Hsm (bf16, A-operand layout for GEMM2)
    // (Hsm aliases the staging buffer; the trailing K-loop barrier guards it.)
    #pragma unroll
    for (int t = 0; t < 16; ++t) {
        int colh = t * 16 + ln;
        float bb = b1[colh];
        #pragma unroll
        for (int i = 0; i < 4; ++i) {
            int row = mw + q * 4 + i;
            float v = acc[t][i] + bb;
            Hsm[row * HPAD + colh] = (bf16)fmaxf(v, 0.0f);
        }
    }
    __syncthreads();

    // GEMM2: X_tile = Hsm @ W2 (K=256, N=32) — 2 n-tiles per wave.
    // B fragments straight from global W2T (L2-hot 16 KB; no LDS staging).
    f32x4 acc2[2] = {};
    #pragma unroll
    for (int k0 = 0; k0 < D_HID; k0 += BK) {
        bf16x8 af2 = *(const bf16x8*)&Hsm[(mw + ln) * HPAD + k0 + q * 8];
        #pragma unroll
        for (int t = 0; t < 2; ++t) {
            bf16x8 bfv = *(const bf16x8*)&W2T[(t * 16 + ln) * D_HID + k0 + q * 8];
            acc2[t] = __builtin_amdgcn_mfma_f32_16x16x32_bf16(af2, bfv, acc2[t], 0, 0, 0);
        }
    }

    // Epilogue 2: X = acc2 + b2 (fp32)
    #pragma unroll
    for (int t = 0; t < 2; ++t) {
        int c = t * 16 + ln;
        float bb = b2[c];
        #pragma unroll
        for (int i = 0; i < 4; ++i) {
            int row = r0 + mw + q * 4 + i;
            if (row < N) X[row * D_OUT + c] = acc2[t][i] + bb;
        }
    }
}

// ---------------- CSR build: histogram -> scan -> reorder -------------------
__global__ __launch_bounds__(256) void hist_kernel(
    const int* __restrict__ Arow, int* __restrict__ counts, int E)
{
    int e = blockIdx.x * 256 + threadIdx.x;
    if (e < E) atomicAdd(&counts[Arow[e]], 1);
}

__global__ __launch_bounds__(256) void scanA_kernel(
    const int* __restrict__ counts, int* __restrict__ offs,
    int* __restrict__ partials, int N)
{
    __shared__ int lds[256];
    int t = threadIdx.x;
    int base = blockIdx.x * SCAN_SPAN + t * SCAN_VPT;
    int v[SCAN_VPT];
    int tsum = 0;
    #pragma unroll
    for (int j = 0; j < SCAN_VPT; ++j) {
        v[j] = (base + j < N) ? counts[base + j] : 0;
        tsum += v[j];
    }
    lds[t] = tsum;
    __syncthreads();
    for (int d = 1; d < 256; d <<= 1) {
        int x = (t >= d) ? lds[t - d] : 0;
        __syncthreads();
        lds[t] += x;
        __syncthreads();
    }
    int run = lds[t] - tsum;
    #pragma unroll
    for (int j = 0; j < SCAN_VPT; ++j) {
        if (base + j < N) offs[base + j] = run;
        run += v[j];
    }
    if (t == 255) partials[blockIdx.x] = lds[255];
}

__global__ __launch_bounds__(256) void scanB_kernel(int* __restrict__ partials, int nb)
{
    __shared__ int lds[256];
    int t = threadIdx.x;
    int v = (t < nb) ? partials[t] : 0;
    lds[t] = v;
    __syncthreads();
    for (int d = 1; d < 256; d <<= 1) {
        int x = (t >= d) ? lds[t - d] : 0;
        __syncthreads();
        lds[t] += x;
        __syncthreads();
    }
    if (t < nb) partials[t] = lds[t] - v;
}

__global__ __launch_bounds__(256) void scanC_kernel(
    int* __restrict__ offs, const int* __restrict__ partials,
    int* __restrict__ cursor, int N)
{
    int i = blockIdx.x * 256 + threadIdx.x;
    if (i < N) {
        int o = offs[i] + partials[i / SCAN_SPAN];
        offs[i] = o;
        cursor[i] = o;
    }
}

// ---------------- reorder, XCD-writer-partitioned ---------------------------
// Grid = NSLICE * ceil(E/256). Block b: edge chunk b>>3, row slice b&7.
// Each edge is seen by 8 blocks (one per slice) and appended by exactly the
// one whose slice contains its row -> correctness independent of dispatch.
// With round-robin block->XCD mapping, each CSR row region has ONE writing
// XCD -> exclusive L2 ownership of frontier lines -> full-line evictions.
__global__ __launch_bounds__(256) void reorder_kernel(
    const int* __restrict__ Arow, const int* __restrict__ Acol,
    const float* __restrict__ Adata, int* __restrict__ cursor,
    int2* __restrict__ pairs, int E, int rps)
{
    int b = blockIdx.x;
    int slice = b & (NSLICE - 1);
    int e = (b >> 3) * 256 + threadIdx.x;
    if (e >= E) return;
    int r = Arow[e];
    if ((unsigned)(r - slice * rps) >= (unsigned)rps) return;
    int p = atomicAdd(&cursor[r], 1);
    int2 pk;
    pk.x = Acol[e];
    pk.y = __float_as_int(Adata[e]);
    pairs[p] = pk;  // single 8B store; frontier lines owned by one XCD
}

// ---------------- reduce: one wave per row, 8 edges in flight ---------------
__global__ __launch_bounds__(256) void reduce_kernel(
    const int* __restrict__ offs, const int* __restrict__ counts,
    const int2* __restrict__ pairs, const float* __restrict__ X,
    float* __restrict__ out, int N)
{
    int w    = threadIdx.x >> 6;
    int lane = threadIdx.x & 63;
    int r    = blockIdx.x * 4 + w;
    if (r >= N) return;
    int slot = lane >> 3;    // edge slot 0..7
    int dg   = lane & 7;     // dim group: dims 4*dg..4*dg+3
    int off  = offs[r];
    int deg  = counts[r];
    f32x4 acc = {0.0f, 0.0f, 0.0f, 0.0f};
    for (int i = slot; i < deg; i += 8) {
        int2  pk = pairs[off + i];       // broadcast across the 8 dg lanes
        float a  = __int_as_float(pk.y);
        f32x4 x  = *(const f32x4*)(X + (long)pk.x * D_OUT + dg * 4);
        acc += a * x;
    }
    // butterfly over slots (strides 8,16,32)
    #pragma unroll
    for (int d = 8; d < 64; d <<= 1) {
        acc[0] += __shfl_xor(acc[0], d, 64);
        acc[1] += __shfl_xor(acc[1], d, 64);
        acc[2] += __shfl_xor(acc[2], d, 64);
        acc[3] += __shfl_xor(acc[3], d, 64);
    }
    if (slot == 0) *(f32x4*)(out + (long)r * D_OUT + dg * 4) = acc;
}

// ---------------- fallback scatter (if ws too small) ------------------------
__global__ __launch_bounds__(256) void scatter_kernel(
    const float* __restrict__ Adata, const int* __restrict__ Arow,
    const int* __restrict__ Acol, const float* __restrict__ X,
    float* __restrict__ out, int E)
{
    int idx = blockIdx.x * 256 + threadIdx.x;
    int e = idx >> 3;
    int g = idx & 7;
    if (e >= E) return;
    int   col = Acol[e];
    int   row = Arow[e];
    float a   = Adata[e];
    float4 x = *(const float4*)(X + (long)col * D_OUT + g * 4);
    float* o = out + (long)row * D_OUT + g * 4;
    unsafeAtomicAdd(o + 0, a * x.x);
    unsafeAtomicAdd(o + 1, a * x.y);
    unsafeAtomicAdd(o + 2, a * x.z);
    unsafeAtomicAdd(o + 3, a * x.w);
}

// ---------------- launch ----------------------------------------------------
extern "C" void kernel_launch(void* const* d_in, const int* in_sizes, int n_in,
                              void* d_out, int out_size, void* d_ws, size_t ws_size,
                              hipStream_t stream)
{
    const float* feat  = (const float*)d_in[0];
    const float* Adata = (const float*)d_in[1];
    const float* W1    = (const float*)d_in[2];
    const float* b1    = (const float*)d_in[3];
    const float* W2    = (const float*)d_in[4];
    const float* b2    = (const float*)d_in[5];
    const int*   Arow  = (const int*)d_in[6];
    const int*   Acol  = (const int*)d_in[7];

    const int N = in_sizes[0] / D_IN;
    const int E = in_sizes[1];

    // --- workspace carve-out (256B aligned segments) ---
    char* p = (char*)d_ws;
    auto alloc = [&](size_t bytes) {
        char* q = p;
        p += (bytes + 255) & ~(size_t)255;
        return q;
    };
    float* X       = (float*)alloc((size_t)N * D_OUT * sizeof(float));
    bf16*  W1T     = (bf16*) alloc((size_t)D_IN * D_HID * sizeof(bf16));
    bf16*  W2T     = (bf16*) alloc((size_t)D_HID * D_OUT * sizeof(bf16));
    int*   counts  = (int*)  alloc((size_t)N * sizeof(int));
    int*   offs    = (int*)  alloc((size_t)N * sizeof(int));
    int*   cursor  = (int*)  alloc((size_t)N * sizeof(int));
    int*   partials= (int*)  alloc(256 * sizeof(int));
    int2*  pairs   = (int2*) alloc((size_t)E * sizeof(int2));
    size_t need = (size_t)(p - (char*)d_ws);
    const bool use_csr = (need <= ws_size);

    float* out = (float*)d_out;

    int prep_elems = D_IN * D_HID + D_HID * D_OUT;
    prep_kernel<<<(prep_elems + 255) / 256, 256, 0, stream>>>(W1, W2, W1T, W2T);

    fused_mlp_kernel<<<(N + BM - 1) / BM, 256, 0, stream>>>(
        feat, W1T, W2T, b1, b2, X, N);

    if (use_csr) {
        hipMemsetAsync(counts, 0, (size_t)N * sizeof(int), stream);
        hist_kernel<<<(E + 255) / 256, 256, 0, stream>>>(Arow, counts, E);
        int nb = (N + SCAN_SPAN - 1) / SCAN_SPAN;   // 49 for N=100000 (<=256)
        scanA_kernel<<<nb, 256, 0, stream>>>(counts, offs, partials, N);
        scanB_kernel<<<1, 256, 0, stream>>>(partials, nb);
        scanC_kernel<<<(N + 255) / 256, 256, 0, stream>>>(offs, partials, cursor, N);
        int rps = (N + NSLICE - 1) / NSLICE;
        reorder_kernel<<<NSLICE * ((E + 255) / 256), 256, 0, stream>>>(
            Arow, Acol, Adata, cursor, pairs, E, rps);
        reduce_kernel<<<(N + 3) / 4, 256, 0, stream>>>(
            offs, counts, pairs, X, out, N);
    } else {
        hipMemsetAsync(out, 0, (size_t)out_size * sizeof(float), stream);
        long scatter_threads = (long)E * 8;
        scatter_kernel<<<(scatter_threads + 255) / 256, 256, 0, stream>>>(
            Adata, Arow, Acol, X, out, E);
    }
}

// Round 5
// 532.458 us; speedup vs baseline: 2.0281x; 1.0056x over previous
//
#include <hip/hip_runtime.h>
#include <hip/hip_bf16.h>

typedef __bf16 bf16;
typedef __attribute__((ext_vector_type(8))) __bf16 bf16x8;
typedef __attribute__((ext_vector_type(4))) float f32x4;

constexpr int D_IN  = 512;
constexpr int D_HID = 256;
constexpr int D_OUT = 32;
constexpr int BM = 64;     // rows per block
constexpr int BK = 64;     // K chunk (two 16x16x32 MFMA deep)
constexpr int HCP = 40;    // Hc chunk-stride (bf16): 80B rows -> 8 bank groups
constexpr int SCAN_VPT  = 8;
constexpr int SCAN_SPAN = 2048;  // 256 threads * 8
constexpr int NSLICE = 8;        // XCD count: writer partitioning

#define GLOBAL_AS(p) ((const __attribute__((address_space(1))) void*)(p))
#define LDS_AS(p)    ((__attribute__((address_space(3))) void*)(p))

// ---------------- prep: W1 -> W1T (bf16, [n][k]), W2 -> W2T (bf16, [n][k]) --
__global__ __launch_bounds__(256) void prep_kernel(
    const float* __restrict__ W1, const float* __restrict__ W2,
    bf16* __restrict__ W1T, bf16* __restrict__ W2T)
{
    int idx = blockIdx.x * 256 + threadIdx.x;
    if (idx < D_IN * D_HID) {
        int k = idx / D_HID, n = idx % D_HID;
        W1T[n * D_IN + k] = (bf16)W1[idx];
    }
    int j = idx - D_IN * D_HID;
    if (j >= 0 && j < D_HID * D_OUT) {
        int k = j / D_OUT, n = j % D_OUT;
        W2T[n * D_HID + k] = (bf16)W2[j];
    }
}

// ---------------- fused MLP: X = relu(feat@W1 + b1) @ W2 + b2 ---------------
// Verified barrier topology (stage -> sync -> MFMA -> sync), BK widened to 64:
// 8 K-steps instead of 16 -> half the vmcnt(0) drains, 2x MFMA per drain.
// GEMM2: h transposed through a 5KB Hc chunk buffer (aliases dead Bsm),
// 8 chunks of [64][32], write->sync->read->sync each (LDS-only, no async).
__global__ __launch_bounds__(256) void fused_mlp_kernel(
    const float* __restrict__ feat,
    const bf16* __restrict__ W1T, const bf16* __restrict__ W2T,
    const float* __restrict__ b1, const float* __restrict__ b2,
    float* __restrict__ X, int N)
{
    // Bsm: [D_HID][BK] bf16 = 32 KB (staging; dead after K-loop)
    // Hc : [BM][HCP]  bf16 = 5 KB, aliases Bsm
    __shared__ __align__(16) char smem[D_HID * BK * sizeof(bf16)];
    bf16* Bsm = (bf16*)smem;
    bf16* Hc  = (bf16*)smem;

    const int tid  = threadIdx.x;
    const int wave = tid >> 6;
    const int lane = tid & 63;
    const int ln   = lane & 15;   // MFMA row/col index
    const int q    = lane >> 4;   // quad 0..3
    const int mw   = wave * 16;   // wave's row block within tile
    const int r0   = blockIdx.x * BM;

    f32x4 acc[16] = {};  // 16 n-tiles of 16x16 per wave (full D_HID)

    // A source: lane (q,ln) owns row mw+ln (fragment layout)
    const long arow = (long)min(r0 + mw + ln, N - 1);
    const float* asrc = feat + arow * D_IN + q * 8;

    for (int k0 = 0; k0 < D_IN; k0 += BK) {   // 8 steps
        // async stage B tile [256][64] from W1T. LDS dest linear (16B * c);
        // GLOBAL slot permuted: phys slot s of row r holds logical s^(r&7).
        #pragma unroll
        for (int i = 0; i < 8; ++i) {
            int c  = i * 256 + wave * 64 + lane;        // 0..2047
            int sl = (c & 7) ^ ((c >> 3) & 7);
            const bf16* gsrc = W1T + ((c >> 3) * D_IN + k0 + sl * 8);
            bf16* lbase = Bsm + (i * 256 + wave * 64) * 8;  // wave-uniform
            __builtin_amdgcn_global_load_lds(GLOBAL_AS(gsrc), LDS_AS(lbase), 16, 0, 0);
        }

        // A fragments for both 32-wide sub-steps: direct global -> registers
        bf16x8 af0, af1;
        {
            float4 f0 = *(const float4*)(asrc + k0);
            float4 f1 = *(const float4*)(asrc + k0 + 4);
            af0[0] = (bf16)f0.x; af0[1] = (bf16)f0.y; af0[2] = (bf16)f0.z; af0[3] = (bf16)f0.w;
            af0[4] = (bf16)f1.x; af0[5] = (bf16)f1.y; af0[6] = (bf16)f1.z; af0[7] = (bf16)f1.w;
            float4 f2 = *(const float4*)(asrc + k0 + 32);
            float4 f3 = *(const float4*)(asrc + k0 + 36);
            af1[0] = (bf16)f2.x; af1[1] = (bf16)f2.y; af1[2] = (bf16)f2.z; af1[3] = (bf16)f2.w;
            af1[4] = (bf16)f3.x; af1[5] = (bf16)f3.y; af1[6] = (bf16)f3.z; af1[7] = (bf16)f3.w;
        }

        __syncthreads();   // drains global_load_lds (compiler vmcnt(0) pre-barrier)

        {
            const int psl0 = (0 * 4 + q) ^ (ln & 7);   // kk=0 phys slot
            #pragma unroll
            for (int t = 0; t < 16; ++t) {
                bf16x8 bfv = *(const bf16x8*)&Bsm[(t * 16 + ln) * BK + psl0 * 8];
                acc[t] = __builtin_amdgcn_mfma_f32_16x16x32_bf16(af0, bfv, acc[t], 0, 0, 0);
            }
            const int psl1 = (1 * 4 + q) ^ (ln & 7);   // kk=1 phys slot
            #pragma unroll
            for (int t = 0; t < 16; ++t) {
                bf16x8 bfv = *(const bf16x8*)&Bsm[(t * 16 + ln) * BK + psl1 * 8];
                acc[t] = __builtin_amdgcn_mfma_f32_16x16x32_bf16(af1, bfv, acc[t], 0, 0, 0);
            }
        }
        __syncthreads();   // protect Bsm for next iteration's staging
    }

    // GEMM2: X_tile = relu(h) @ W2, transposed chunkwise through Hc.
    // Chunk cc covers h cols 32cc..32cc+31 (acc tiles t=2cc, 2cc+1).
    f32x4 acc2[2] = {};
    #pragma unroll
    for (int cc = 0; cc < 8; ++cc) {
        #pragma unroll
        for (int tt = 0; tt < 2; ++tt) {
            int t = cc * 2 + tt;
            float bb = b1[t * 16 + ln];
            #pragma unroll
            for (int i = 0; i < 4; ++i) {
                int row = mw + q * 4 + i;
                float v = acc[t][i] + bb;
                Hc[row * HCP + tt * 16 + ln] = (bf16)fmaxf(v, 0.0f);
            }
        }
        __syncthreads();   // Hc chunk visible (first iter also: Bsm reads done)
        bf16x8 af2 = *(const bf16x8*)&Hc[(mw + ln) * HCP + q * 8];
        int kg = cc * 32 + q * 8;
        #pragma unroll
        for (int t2 = 0; t2 < 2; ++t2) {
            bf16x8 bfv = *(const bf16x8*)&W2T[(t2 * 16 + ln) * D_HID + kg];
            acc2[t2] = __builtin_amdgcn_mfma_f32_16x16x32_bf16(af2, bfv, acc2[t2], 0, 0, 0);
        }
        __syncthreads();   // before next chunk overwrites Hc
    }

    // Epilogue: X = acc2 + b2 (fp32)
    #pragma unroll
    for (int t = 0; t < 2; ++t) {
        int c = t * 16 + ln;
        float bb = b2[c];
        #pragma unroll
        for (int i = 0; i < 4; ++i) {
            int row = r0 + mw + q * 4 + i;
            if (row < N) X[row * D_OUT + c] = acc2[t][i] + bb;
        }
    }
}

// ---------------- CSR build: histogram -> scan -> reorder -------------------
// hist XCD-sliced like reorder: all atomics to a row region issue from one
// XCD -> L2-local atomic turnaround, no cross-XCD counter-line bouncing.
__global__ __launch_bounds__(256) void hist_kernel(
    const int* __restrict__ Arow, int* __restrict__ counts, int E, int rps)
{
    int b = blockIdx.x;
    int slice = b & (NSLICE - 1);
    int e = (b >> 3) * 256 + threadIdx.x;
    if (e >= E) return;
    int r = Arow[e];
    if ((unsigned)(r - slice * rps) >= (unsigned)rps) return;
    atomicAdd(&counts[r], 1);
}

__global__ __launch_bounds__(256) void scanA_kernel(
    const int* __restrict__ counts, int* __restrict__ offs,
    int* __restrict__ partials, int N)
{
    __shared__ int lds[256];
    int t = threadIdx.x;
    int base = blockIdx.x * SCAN_SPAN + t * SCAN_VPT;
    int v[SCAN_VPT];
    int tsum = 0;
    #pragma unroll
    for (int j = 0; j < SCAN_VPT; ++j) {
        v[j] = (base + j < N) ? counts[base + j] : 0;
        tsum += v[j];
    }
    lds[t] = tsum;
    __syncthreads();
    for (int d = 1; d < 256; d <<= 1) {
        int x = (t >= d) ? lds[t - d] : 0;
        __syncthreads();
        lds[t] += x;
        __syncthreads();
    }
    int run = lds[t] - tsum;
    #pragma unroll
    for (int j = 0; j < SCAN_VPT; ++j) {
        if (base + j < N) offs[base + j] = run;
        run += v[j];
    }
    if (t == 255) partials[blockIdx.x] = lds[255];
}

__global__ __launch_bounds__(256) void scanB_kernel(int* __restrict__ partials, int nb)
{
    __shared__ int lds[256];
    int t = threadIdx.x;
    int v = (t < nb) ? partials[t] : 0;
    lds[t] = v;
    __syncthreads();
    for (int d = 1; d < 256; d <<= 1) {
        int x = (t >= d) ? lds[t - d] : 0;
        __syncthreads();
        lds[t] += x;
        __syncthreads();
    }
    if (t < nb) partials[t] = lds[t] - v;
}

__global__ __launch_bounds__(256) void scanC_kernel(
    int* __restrict__ offs, const int* __restrict__ partials,
    int* __restrict__ cursor, int N)
{
    int i = blockIdx.x * 256 + threadIdx.x;
    if (i < N) {
        int o = offs[i] + partials[i / SCAN_SPAN];
        offs[i] = o;
        cursor[i] = o;
    }
}

// ---------------- reorder, XCD-writer-partitioned ---------------------------
__global__ __launch_bounds__(256) void reorder_kernel(
    const int* __restrict__ Arow, const int* __restrict__ Acol,
    const float* __restrict__ Adata, int* __restrict__ cursor,
    int2* __restrict__ pairs, int E, int rps)
{
    int b = blockIdx.x;
    int slice = b & (NSLICE - 1);
    int e = (b >> 3) * 256 + threadIdx.x;
    if (e >= E) return;
    int r = Arow[e];
    if ((unsigned)(r - slice * rps) >= (unsigned)rps) return;
    int p = atomicAdd(&cursor[r], 1);
    int2 pk;
    pk.x = Acol[e];
    pk.y = __float_as_int(Adata[e]);
    pairs[p] = pk;  // single 8B store; frontier lines owned by one XCD
}

// ---------------- reduce: one wave per row, 8 edges in flight ---------------
__global__ __launch_bounds__(256) void reduce_kernel(
    const int* __restrict__ offs, const int* __restrict__ counts,
    const int2* __restrict__ pairs, const float* __restrict__ X,
    float* __restrict__ out, int N)
{
    int w    = threadIdx.x >> 6;
    int lane = threadIdx.x & 63;
    int r    = blockIdx.x * 4 + w;
    if (r >= N) return;
    int slot = lane >> 3;    // edge slot 0..7
    int dg   = lane & 7;     // dim group: dims 4*dg..4*dg+3
    int off  = offs[r];
    int deg  = counts[r];
    f32x4 acc = {0.0f, 0.0f, 0.0f, 0.0f};
    for (int i = slot; i < deg; i += 8) {
        int2  pk = pairs[off + i];       // broadcast across the 8 dg lanes
        float a  = __int_as_float(pk.y);
        f32x4 x  = *(const f32x4*)(X + (long)pk.x * D_OUT + dg * 4);
        acc += a * x;
    }
    // butterfly over slots (strides 8,16,32)
    #pragma unroll
    for (int d = 8; d < 64; d <<= 1) {
        acc[0] += __shfl_xor(acc[0], d, 64);
        acc[1] += __shfl_xor(acc[1], d, 64);
        acc[2] += __shfl_xor(acc[2], d, 64);
        acc[3] += __shfl_xor(acc[3], d, 64);
    }
    if (slot == 0) *(f32x4*)(out + (long)r * D_OUT + dg * 4) = acc;
}

// ---------------- fallback scatter (if ws too small) ------------------------
__global__ __launch_bounds__(256) void scatter_kernel(
    const float* __restrict__ Adata, const int* __restrict__ Arow,
    const int* __restrict__ Acol, const float* __restrict__ X,
    float* __restrict__ out, int E)
{
    int idx = blockIdx.x * 256 + threadIdx.x;
    int e = idx >> 3;
    int g = idx & 7;
    if (e >= E) return;
    int   col = Acol[e];
    int   row = Arow[e];
    float a   = Adata[e];
    float4 x = *(const float4*)(X + (long)col * D_OUT + g * 4);
    float* o = out + (long)row * D_OUT + g * 4;
    unsafeAtomicAdd(o + 0, a * x.x);
    unsafeAtomicAdd(o + 1, a * x.y);
    unsafeAtomicAdd(o + 2, a * x.z);
    unsafeAtomicAdd(o + 3, a * x.w);
}

// ---------------- launch ----------------------------------------------------
extern "C" void kernel_launch(void* const* d_in, const int* in_sizes, int n_in,
                              void* d_out, int out_size, void* d_ws, size_t ws_size,
                              hipStream_t stream)
{
    const float* feat  = (const float*)d_in[0];
    const float* Adata = (const float*)d_in[1];
    const float* W1    = (const float*)d_in[2];
    const float* b1    = (const float*)d_in[3];
    const float* W2    = (const float*)d_in[4];
    const float* b2    = (const float*)d_in[5];
    const int*   Arow  = (const int*)d_in[6];
    const int*   Acol  = (const int*)d_in[7];

    const int N = in_sizes[0] / D_IN;
    const int E = in_sizes[1];

    // --- workspace carve-out (256B aligned segments) ---
    char* p = (char*)d_ws;
    auto alloc = [&](size_t bytes) {
        char* q = p;
        p += (bytes + 255) & ~(size_t)255;
        return q;
    };
    float* X       = (float*)alloc((size_t)N * D_OUT * sizeof(float));
    bf16*  W1T     = (bf16*) alloc((size_t)D_IN * D_HID * sizeof(bf16));
    bf16*  W2T     = (bf16*) alloc((size_t)D_HID * D_OUT * sizeof(bf16));
    int*   counts  = (int*)  alloc((size_t)N * sizeof(int));
    int*   offs    = (int*)  alloc((size_t)N * sizeof(int));
    int*   cursor  = (int*)  alloc((size_t)N * sizeof(int));
    int*   partials= (int*)  alloc(256 * sizeof(int));
    int2*  pairs   = (int2*) alloc((size_t)E * sizeof(int2));
    size_t need = (size_t)(p - (char*)d_ws);
    const bool use_csr = (need <= ws_size);

    float* out = (float*)d_out;

    int prep_elems = D_IN * D_HID + D_HID * D_OUT;
    prep_kernel<<<(prep_elems + 255) / 256, 256, 0, stream>>>(W1, W2, W1T, W2T);

    fused_mlp_kernel<<<(N + BM - 1) / BM, 256, 0, stream>>>(
        feat, W1T, W2T, b1, b2, X, N);

    if (use_csr) {
        hipMemsetAsync(counts, 0, (size_t)N * sizeof(int), stream);
        int rps = (N + NSLICE - 1) / NSLICE;
        hist_kernel<<<NSLICE * ((E + 255) / 256), 256, 0, stream>>>(
            Arow, counts, E, rps);
        int nb = (N + SCAN_SPAN - 1) / SCAN_SPAN;   // 49 for N=100000 (<=256)
        scanA_kernel<<<nb, 256, 0, stream>>>(counts, offs, partials, N);
        scanB_kernel<<<1, 256, 0, stream>>>(partials, nb);
        scanC_kernel<<<(N + 255) / 256, 256, 0, stream>>>(offs, partials, cursor, N);
        reorder_kernel<<<NSLICE * ((E + 255) / 256), 256, 0, stream>>>(
            Arow, Acol, Adata, cursor, pairs, E, rps);
        reduce_kernel<<<(N + 3) / 4, 256, 0, stream>>>(
            offs, counts, pairs, X, out, N);
    } else {
        hipMemsetAsync(out, 0, (size_t)out_size * sizeof(float), stream);
        long scatter_threads = (long)E * 8;
        scatter_kernel<<<(scatter_threads + 255) / 256, 256, 0, stream>>>(
            Adata, Arow, Acol, X, out, E);
    }
}